// Round 1
// baseline (325.343 us; speedup 1.0000x reference)
//
#include <hip/hip_runtime.h>
#include <hip/hip_bf16.h>

#define N_NODES 8192
#define D_FEAT 128
#define NWORDS 8   // 8 u64 words of band codes per node (64 bands x 8 bits)

typedef __bf16 bf16x8 __attribute__((ext_vector_type(8)));
typedef float f32x4 __attribute__((ext_vector_type(4)));
typedef unsigned long long u64;

// ---------------- Kernel A: normalize rows of z -> bf16 zn ----------------
// One wave per node; lane holds 2 floats; butterfly shuffle reduce for ||z||.
__global__ __launch_bounds__(256) void norm_kernel(const float* __restrict__ z,
                                                   unsigned short* __restrict__ zn) {
  int wv = threadIdx.x >> 6, lane = threadIdx.x & 63;
  int node = blockIdx.x * 4 + wv;
  const float2* row = (const float2*)(z + (size_t)node * D_FEAT);
  float2 v = row[lane];
  float ss = v.x * v.x + v.y * v.y;
#pragma unroll
  for (int off = 32; off > 0; off >>= 1) ss += __shfl_xor(ss, off);
  float inv = rsqrtf(ss);
  __hip_bfloat16 a = __float2bfloat16(v.x * inv);
  __hip_bfloat16 b = __float2bfloat16(v.y * inv);
  unsigned int packed = (unsigned int)(*(unsigned short*)&a) |
                        ((unsigned int)(*(unsigned short*)&b) << 16);
  ((unsigned int*)zn)[(size_t)node * 64 + lane] = packed;
}

// ---------------- Kernel B: LSH band codes ----------------
// Block = 256 threads (4 waves) handles 16 nodes, all 8 code words.
// Wave wv handles words {2wv, 2wv+1}; lane = projection-within-word.
// Bit index within u64 word == lane index, so the word is one __ballot.
// z reads are wave-uniform -> scalar loads; H reads are lane-coalesced.
__global__ __launch_bounds__(256) void codes_kernel(const float* __restrict__ z,
                                                    const float* __restrict__ H,
                                                    u64* __restrict__ codes) {
  int tid = threadIdx.x;
  int wv = tid >> 6, lane = tid & 63;
  int base = blockIdx.x * 16;
#pragma unroll
  for (int wi = 0; wi < 2; ++wi) {
    int word = wv * 2 + wi;
    int col = word * 64 + lane;
    float acc[16];
#pragma unroll
    for (int n = 0; n < 16; ++n) acc[n] = 0.f;
    for (int k = 0; k < D_FEAT; ++k) {
      float h = H[(size_t)k * 512 + col];
#pragma unroll
      for (int n = 0; n < 16; ++n)
        acc[n] += z[(size_t)(base + n) * D_FEAT + k] * h;
    }
#pragma unroll
    for (int n = 0; n < 16; ++n) {
      u64 b = __ballot(acc[n] > 0.0f);
      if (lane == 0) codes[(size_t)(base + n) * NWORDS + word] = b;
    }
  }
}

// ---------------- Kernel C: S = zn zn^T tile + epilogue ----------------
// 128x128 output tile per block, 4 waves each computing a 64x64 sub-tile
// via 4x4 MFMA 16x16x32 bf16 tiles; K=128 fully unrolled (no K staging loop).
// LDS tiles XOR-swizzled in 16B chunks: conflict-free b128 frag reads AND
// total static LDS = exactly 64 KB (fits the per-block limit, 2 blocks/CU).
__global__ __launch_bounds__(256, 2) void sim_kernel(const unsigned short* __restrict__ zn,
                                                     const u64* __restrict__ codes,
                                                     float* __restrict__ out) {
  __shared__ unsigned short As[128][128];
  __shared__ unsigned short Bs[128][128];
  int tid = threadIdx.x;
  int bm = blockIdx.x, bn = blockIdx.y;

  const uint4* gA = (const uint4*)(zn + (size_t)bm * 128 * D_FEAT);
  const uint4* gB = (const uint4*)(zn + (size_t)bn * 128 * D_FEAT);
#pragma unroll
  for (int r = 0; r < 8; ++r) {
    int idx = tid + 256 * r;        // 16B-chunk index, 0..2047
    int row = idx >> 4, c16 = idx & 15;
    int cs = c16 ^ (row & 15);      // XOR swizzle
    ((uint4*)&As[row][0])[cs] = gA[idx];
    ((uint4*)&Bs[row][0])[cs] = gB[idx];
  }
  __syncthreads();

  int wv = tid >> 6, lane = tid & 63;
  int wm = (wv >> 1) * 64, wn = (wv & 1) * 64;
  int m16 = lane & 15, g = lane >> 4;

  f32x4 acc[4][4] = {};

#pragma unroll
  for (int kc = 0; kc < 4; ++kc) {
    bf16x8 fa[4], fb[4];
    int chunk = kc * 4 + g;
    int cs = (chunk ^ m16) * 8;     // row bases are multiples of 16 -> row&15 == m16
#pragma unroll
    for (int t = 0; t < 4; ++t) {
      fa[t] = *(const bf16x8*)&As[wm + t * 16 + m16][cs];
      fb[t] = *(const bf16x8*)&Bs[wn + t * 16 + m16][cs];
    }
#pragma unroll
    for (int tm = 0; tm < 4; ++tm)
#pragma unroll
      for (int tn = 0; tn < 4; ++tn)
        acc[tm][tn] = __builtin_amdgcn_mfma_f32_16x16x32_bf16(fa[tm], fb[tn], acc[tm][tn], 0, 0, 0);
  }

  // Epilogue: C/D layout col=lane&15, row=g*4+r (guide §3, m89/m91 verified).
#pragma unroll
  for (int tm = 0; tm < 4; ++tm) {
#pragma unroll
    for (int tn = 0; tn < 4; ++tn) {
      int j = bn * 128 + wn + tn * 16 + m16;
      int ibase = bm * 128 + wm + tm * 16 + g * 4;
      f32x4 c = acc[tm][tn];
#pragma unroll
      for (int r = 0; r < 4; ++r) {
        int i = ibase + r;
        float s = c[r];
        float val = 0.0f;
        if (i == j) {
          val = 1.0f;
        } else if (s > 0.75f) {
          // rare path: check band-code collision (any equal byte in 64 bands)
          bool hit = false;
#pragma unroll
          for (int w = 0; w < NWORDS; ++w) {
            u64 x = codes[(size_t)i * NWORDS + w] ^ codes[(size_t)j * NWORDS + w];
            u64 hz = (x - 0x0101010101010101ULL) & ~x & 0x8080808080808080ULL;
            hit |= (hz != 0);
          }
          if (hit) val = s;
        }
        out[(size_t)i * N_NODES + j] = val;
      }
    }
  }
}

extern "C" void kernel_launch(void* const* d_in, const int* in_sizes, int n_in,
                              void* d_out, int out_size, void* d_ws, size_t ws_size,
                              hipStream_t stream) {
  const float* z = (const float*)d_in[0];   // [8192, 128] fp32
  const float* H = (const float*)d_in[1];   // [128, 512] fp32
  // d_in[2] = edge_index, unused by the reference forward.
  float* out = (float*)d_out;               // [8192, 8192] fp32

  unsigned short* zn = (unsigned short*)d_ws;                               // 2 MB bf16
  u64* codes = (u64*)((char*)d_ws + (size_t)N_NODES * D_FEAT * 2);          // 512 KB

  norm_kernel<<<N_NODES / 4, 256, 0, stream>>>(z, zn);
  codes_kernel<<<N_NODES / 16, 256, 0, stream>>>(z, H, codes);
  sim_kernel<<<dim3(64, 64), 256, 0, stream>>>(zn, codes, out);
}

// Round 2
// 311.299 us; speedup vs baseline: 1.0451x; 1.0451x over previous
//
#include <hip/hip_runtime.h>
#include <hip/hip_bf16.h>

#define N_NODES 8192
#define D_FEAT 128
#define NWORDS 8   // 8 u64 words of band codes per node (64 bands x 8 bits)

typedef __bf16 bf16x8 __attribute__((ext_vector_type(8)));
typedef float f32x4 __attribute__((ext_vector_type(4)));
typedef unsigned long long u64;

// ---------------- Kernel A: normalize rows of z -> bf16 zn ----------------
// One wave per node; lane holds 2 floats; butterfly shuffle reduce for ||z||.
__global__ __launch_bounds__(256) void norm_kernel(const float* __restrict__ z,
                                                   unsigned short* __restrict__ zn) {
  int wv = threadIdx.x >> 6, lane = threadIdx.x & 63;
  int node = blockIdx.x * 4 + wv;
  const float2* row = (const float2*)(z + (size_t)node * D_FEAT);
  float2 v = row[lane];
  float ss = v.x * v.x + v.y * v.y;
#pragma unroll
  for (int off = 32; off > 0; off >>= 1) ss += __shfl_xor(ss, off);
  float inv = rsqrtf(ss);
  __hip_bfloat16 a = __float2bfloat16(v.x * inv);
  __hip_bfloat16 b = __float2bfloat16(v.y * inv);
  unsigned int packed = (unsigned int)(*(unsigned short*)&a) |
                        ((unsigned int)(*(unsigned short*)&b) << 16);
  ((unsigned int*)zn)[(size_t)node * 64 + lane] = packed;
}

// ---------------- Kernel B: LSH band codes ----------------
// Block = 256 threads (4 waves) handles 16 nodes, all 8 code words.
// Wave wv handles words {2wv, 2wv+1}; lane = projection-within-word, so the
// whole u64 code word is one __ballot.
// z is read as wave-uniform float4 chunks (scalar/broadcast loads, hoisted
// out of the word loop -> read once per k-chunk); H reads are lane-coalesced.
// VALU floor ~7 us (1.07 GFLOP fp32); previous version serialized on 16
// narrow scalar loads + lgkmcnt(0) per k-iteration.
__global__ __launch_bounds__(256) void codes_kernel(const float* __restrict__ z,
                                                    const float* __restrict__ H,
                                                    u64* __restrict__ codes) {
  int tid = threadIdx.x;
  int wv = tid >> 6, lane = tid & 63;
  int base = blockIdx.x * 16;
  const float4* z4 = (const float4*)z;  // node row = 32 float4

  float acc[2][16];
#pragma unroll
  for (int wi = 0; wi < 2; ++wi)
#pragma unroll
    for (int n = 0; n < 16; ++n) acc[wi][n] = 0.f;

  for (int k4 = 0; k4 < 32; ++k4) {
    // wave-uniform z chunk: 16 nodes x 4 k-values (independent wide loads)
    float4 zv[16];
#pragma unroll
    for (int n = 0; n < 16; ++n) zv[n] = z4[(size_t)(base + n) * 32 + k4];
#pragma unroll
    for (int wi = 0; wi < 2; ++wi) {
      int col = (wv * 2 + wi) * 64 + lane;
      float4 h;
      h.x = H[(size_t)(k4 * 4 + 0) * 512 + col];
      h.y = H[(size_t)(k4 * 4 + 1) * 512 + col];
      h.z = H[(size_t)(k4 * 4 + 2) * 512 + col];
      h.w = H[(size_t)(k4 * 4 + 3) * 512 + col];
#pragma unroll
      for (int n = 0; n < 16; ++n)
        acc[wi][n] += zv[n].x * h.x + zv[n].y * h.y + zv[n].z * h.z + zv[n].w * h.w;
    }
  }

#pragma unroll
  for (int wi = 0; wi < 2; ++wi) {
    int word = wv * 2 + wi;
#pragma unroll
    for (int n = 0; n < 16; ++n) {
      u64 b = __ballot(acc[wi][n] > 0.0f);
      if (lane == 0) codes[(size_t)(base + n) * NWORDS + word] = b;
    }
  }
}

// ---------------- Kernel C: S = zn zn^T tile + epilogue ----------------
// 128x128 output tile per block, 4 waves each computing a 64x64 sub-tile
// via 4x4 MFMA 16x16x32 bf16 tiles; K=128 fully unrolled.
// bf16 LDS tiles XOR-swizzled in 16B chunks (conflict-free b128 frag reads).
// Epilogue: values (diag / s>0.75 / rare collide check) computed in MFMA
// C-layout, staged through the SAME 64 KB LDS as fp32 (float4-granular XOR
// swizzle; write side 2-way = free, read side balanced), then stored as
// global_store_dwordx4 with 512B-contiguous lane segments (16 stores/thread
// instead of 64 scalar stores + 64 addr calcs).
__global__ __launch_bounds__(256, 2) void sim_kernel(const unsigned short* __restrict__ zn,
                                                     const u64* __restrict__ codes,
                                                     float* __restrict__ out) {
  __shared__ __align__(16) unsigned char smem_raw[65536];
  unsigned short (*As)[128] = (unsigned short (*)[128])smem_raw;            // 32 KB
  unsigned short (*Bs)[128] = (unsigned short (*)[128])(smem_raw + 32768);  // 32 KB
  float* fS = (float*)smem_raw;                                             // 64 KB alias

  int tid = threadIdx.x;
  int bm = blockIdx.x, bn = blockIdx.y;

  const uint4* gA = (const uint4*)(zn + (size_t)bm * 128 * D_FEAT);
  const uint4* gB = (const uint4*)(zn + (size_t)bn * 128 * D_FEAT);
#pragma unroll
  for (int r = 0; r < 8; ++r) {
    int idx = tid + 256 * r;        // 16B-chunk index, 0..2047
    int row = idx >> 4, c16 = idx & 15;
    int cs = c16 ^ (row & 15);      // XOR swizzle
    ((uint4*)&As[row][0])[cs] = gA[idx];
    ((uint4*)&Bs[row][0])[cs] = gB[idx];
  }
  __syncthreads();

  int wv = tid >> 6, lane = tid & 63;
  int wm = (wv >> 1) * 64, wn = (wv & 1) * 64;
  int m16 = lane & 15, g = lane >> 4;

  f32x4 acc[4][4] = {};

#pragma unroll
  for (int kc = 0; kc < 4; ++kc) {
    bf16x8 fa[4], fb[4];
    int chunk = kc * 4 + g;
    int cs = (chunk ^ m16) * 8;     // row bases are multiples of 16 -> row&15 == m16
#pragma unroll
    for (int t = 0; t < 4; ++t) {
      fa[t] = *(const bf16x8*)&As[wm + t * 16 + m16][cs];
      fb[t] = *(const bf16x8*)&Bs[wn + t * 16 + m16][cs];
    }
#pragma unroll
    for (int tm = 0; tm < 4; ++tm)
#pragma unroll
      for (int tn = 0; tn < 4; ++tn)
        acc[tm][tn] = __builtin_amdgcn_mfma_f32_16x16x32_bf16(fa[tm], fb[tn], acc[tm][tn], 0, 0, 0);
  }

  __syncthreads();   // all waves done reading As/Bs before aliasing as fS

  // Epilogue phase 1: compute final values in C-layout, write fp32 tile to
  // swizzled LDS. C/D layout: col=lane&15, row=g*4+r (m89/m91 verified).
#pragma unroll
  for (int tm = 0; tm < 4; ++tm) {
#pragma unroll
    for (int tn = 0; tn < 4; ++tn) {
      int col = wn + tn * 16 + m16;           // tile-local col
      int j = bn * 128 + col;
      f32x4 c = acc[tm][tn];
#pragma unroll
      for (int r = 0; r < 4; ++r) {
        int row = wm + tm * 16 + g * 4 + r;   // tile-local row
        int i = bm * 128 + row;
        float s = c[r];
        float val = 0.0f;
        if (i == j) {
          val = 1.0f;
        } else if (s > 0.75f) {
          // rare path: check band-code collision (any equal byte in 64 bands)
          bool hit = false;
#pragma unroll
          for (int w = 0; w < NWORDS; ++w) {
            u64 x = codes[(size_t)i * NWORDS + w] ^ codes[(size_t)j * NWORDS + w];
            u64 hz = (x - 0x0101010101010101ULL) & ~x & 0x8080808080808080ULL;
            hit |= (hz != 0);
          }
          if (hit) val = s;
        }
        // float4-granular XOR swizzle: chunk' = (col>>2) ^ (row&31)
        fS[row * 128 + ((((col >> 2) ^ (row & 31)) << 2) | (col & 3))] = val;
      }
    }
  }
  __syncthreads();

  // Epilogue phase 2: coalesced dwordx4 stores (lanes 0-31 cover one full
  // 512B row-half... actually one full row = 32 chunks; 2 rows per instr).
#pragma unroll
  for (int r = 0; r < 16; ++r) {
    int slot = tid + 256 * r;                 // 0..4095 float4 slots
    int row = slot >> 5, chunk = slot & 31;
    float4 v = *(const float4*)&fS[row * 128 + (((chunk ^ (row & 31)) << 2))];
    *(float4*)&out[(size_t)(bm * 128 + row) * N_NODES + bn * 128 + chunk * 4] = v;
  }
}

extern "C" void kernel_launch(void* const* d_in, const int* in_sizes, int n_in,
                              void* d_out, int out_size, void* d_ws, size_t ws_size,
                              hipStream_t stream) {
  const float* z = (const float*)d_in[0];   // [8192, 128] fp32
  const float* H = (const float*)d_in[1];   // [128, 512] fp32
  // d_in[2] = edge_index, unused by the reference forward.
  float* out = (float*)d_out;               // [8192, 8192] fp32

  unsigned short* zn = (unsigned short*)d_ws;                               // 2 MB bf16
  u64* codes = (u64*)((char*)d_ws + (size_t)N_NODES * D_FEAT * 2);          // 512 KB

  norm_kernel<<<N_NODES / 4, 256, 0, stream>>>(z, zn);
  codes_kernel<<<N_NODES / 16, 256, 0, stream>>>(z, H, codes);
  sim_kernel<<<dim3(64, 64), 256, 0, stream>>>(zn, codes, out);
}